// Round 3
// baseline (1214.078 us; speedup 1.0000x reference)
//
#include <hip/hip_runtime.h>
#include <cstddef>
#include <cstdint>

#define N_NODES   100000
#define N_EDGES   1600000
#define N_GRAPHS  512
#define HIDDEN    128
#define N_LAYERS  3

#define SCAN_BS   1024
#define SCAN_NB   ((N_NODES + SCAN_BS - 1) / SCAN_BS)   // 98

// ---------------------------------------------------------------------------
// CSR build (by dst): histogram -> hierarchical scan -> scatter
// 8 edges/thread: int4 coalesced index loads + 8 independent atomic chains
// (scatter is atomic-return latency bound, not BW bound -> ILP is the fix)
// ---------------------------------------------------------------------------
__global__ void deg_kernel(const int* __restrict__ dst, int* __restrict__ deg) {
    int tid = blockIdx.x * blockDim.x + threadIdx.x;
    int e0 = tid * 8;
    if (e0 >= N_EDGES) return;
    int4 d0 = ((const int4*)dst)[tid * 2 + 0];
    int4 d1 = ((const int4*)dst)[tid * 2 + 1];
    atomicAdd(&deg[d0.x], 1);
    atomicAdd(&deg[d0.y], 1);
    atomicAdd(&deg[d0.z], 1);
    atomicAdd(&deg[d0.w], 1);
    atomicAdd(&deg[d1.x], 1);
    atomicAdd(&deg[d1.y], 1);
    atomicAdd(&deg[d1.z], 1);
    atomicAdd(&deg[d1.w], 1);
}

// per-block inclusive scan of deg -> scanned; per-block totals -> bsums
__global__ __launch_bounds__(SCAN_BS) void scan_blocks_kernel(const int* __restrict__ deg,
                                                              int* __restrict__ scanned,
                                                              int* __restrict__ bsums) {
    __shared__ int tmp[SCAN_BS];
    const int t = threadIdx.x;
    const int i = blockIdx.x * SCAN_BS + t;
    int v = (i < N_NODES) ? deg[i] : 0;
    tmp[t] = v;
    __syncthreads();
#pragma unroll
    for (int off = 1; off < SCAN_BS; off <<= 1) {
        int u = (t >= off) ? tmp[t - off] : 0;
        __syncthreads();
        tmp[t] += u;
        __syncthreads();
    }
    if (i < N_NODES) scanned[i] = tmp[t];
    if (t == SCAN_BS - 1) bsums[blockIdx.x] = tmp[t];
}

// single small block: in-place inclusive scan of the 98 block sums
__global__ __launch_bounds__(128) void scan_tops_kernel(int* __restrict__ bsums) {
    __shared__ int tmp[128];
    const int t = threadIdx.x;
    tmp[t] = (t < SCAN_NB) ? bsums[t] : 0;
    __syncthreads();
#pragma unroll
    for (int off = 1; off < 128; off <<= 1) {
        int u = (t >= off) ? tmp[t - off] : 0;
        __syncthreads();
        tmp[t] += u;
        __syncthreads();
    }
    if (t < SCAN_NB) bsums[t] = tmp[t];
}

// row_ptr[i+1] = offset(b) + scanned[i];  posb[i] = row_ptr[i] (row start)
__global__ __launch_bounds__(SCAN_BS) void scan_finalize_kernel(const int* __restrict__ deg,
                                                                const int* __restrict__ scanned,
                                                                const int* __restrict__ bsums,
                                                                int* __restrict__ row_ptr,
                                                                int* __restrict__ posb) {
    const int b = blockIdx.x;
    const int i = b * SCAN_BS + threadIdx.x;
    if (i >= N_NODES) return;
    const int off = (b > 0) ? bsums[b - 1] : 0;
    const int inc = off + scanned[i];
    row_ptr[i + 1] = inc;
    posb[i] = inc - deg[i];
    if (i == 0) row_ptr[0] = 0;
}

__global__ void scatter_kernel(const int* __restrict__ src, const int* __restrict__ dst,
                               int* __restrict__ pos, int* __restrict__ csr_src) {
    int tid = blockIdx.x * blockDim.x + threadIdx.x;
    int e0 = tid * 8;
    if (e0 >= N_EDGES) return;
    int4 d0 = ((const int4*)dst)[tid * 2 + 0];
    int4 d1 = ((const int4*)dst)[tid * 2 + 1];
    int4 s0 = ((const int4*)src)[tid * 2 + 0];
    int4 s1 = ((const int4*)src)[tid * 2 + 1];
    // 8 independent atomic->store chains in flight per thread
    int p0 = atomicAdd(&pos[d0.x], 1);
    int p1 = atomicAdd(&pos[d0.y], 1);
    int p2 = atomicAdd(&pos[d0.z], 1);
    int p3 = atomicAdd(&pos[d0.w], 1);
    int p4 = atomicAdd(&pos[d1.x], 1);
    int p5 = atomicAdd(&pos[d1.y], 1);
    int p6 = atomicAdd(&pos[d1.z], 1);
    int p7 = atomicAdd(&pos[d1.w], 1);
    csr_src[p0] = s0.x;
    csr_src[p1] = s0.y;
    csr_src[p2] = s0.z;
    csr_src[p3] = s0.w;
    csr_src[p4] = s1.x;
    csr_src[p5] = s1.y;
    csr_src[p6] = s1.z;
    csr_src[p7] = s1.w;
}

// ---------------------------------------------------------------------------
// GIN aggregation: Z[i] = X[i] + sum_{j in N_in(i)} X[j]
// one wave (64 lanes) per node, float2 per lane => 512B coalesced row reads
// ---------------------------------------------------------------------------
__global__ void gather_kernel(const float* __restrict__ X, float* __restrict__ Z,
                              const int* __restrict__ row_ptr,
                              const int* __restrict__ csr_src) {
    int wave = (blockIdx.x * blockDim.x + threadIdx.x) >> 6;
    int lane = threadIdx.x & 63;
    if (wave >= N_NODES) return;
    const int i = wave;
    float2 acc = ((const float2*)(X + (size_t)i * HIDDEN))[lane];
    int k = row_ptr[i];
    const int end = row_ptr[i + 1];
    // 4-deep unroll: 4 independent row loads in flight to hide LLC latency
    for (; k + 4 <= end; k += 4) {
        int n0 = csr_src[k + 0];
        int n1 = csr_src[k + 1];
        int n2 = csr_src[k + 2];
        int n3 = csr_src[k + 3];
        float2 v0 = ((const float2*)(X + (size_t)n0 * HIDDEN))[lane];
        float2 v1 = ((const float2*)(X + (size_t)n1 * HIDDEN))[lane];
        float2 v2 = ((const float2*)(X + (size_t)n2 * HIDDEN))[lane];
        float2 v3 = ((const float2*)(X + (size_t)n3 * HIDDEN))[lane];
        acc.x += v0.x + v1.x + v2.x + v3.x;
        acc.y += v0.y + v1.y + v2.y + v3.y;
    }
    for (; k < end; ++k) {
        int n = csr_src[k];
        float2 v = ((const float2*)(X + (size_t)n * HIDDEN))[lane];
        acc.x += v.x;
        acc.y += v.y;
    }
    ((float2*)(Z + (size_t)i * HIDDEN))[lane] = acc;
}

// ---------------------------------------------------------------------------
// C[M x 128] = relu(A[M x 128] @ W[128 x 128] + bias)
// 128-row tile / block of 256 threads; 8x8 acc per thread; k staged in LDS
// chunks of 32 with A transposed to [k][row] so all LDS reads are b128-able.
// LDS = 32*129*4 + 32*128*4 = 33 KB -> 4 blocks/CU.
// ---------------------------------------------------------------------------
__global__ __launch_bounds__(256, 4) void mm_kernel(const float* __restrict__ A,
                                                    const float* __restrict__ W,
                                                    const float* __restrict__ bias,
                                                    float* __restrict__ C, int M) {
    __shared__ float As[32][129];   // [k][row], +1 pad
    __shared__ float Ws[32][128];   // [k][col]
    const int t  = threadIdx.x;
    const int tx = t & 15;          // col group: cols tx*4..+3 and 64+tx*4..+3
    const int ty = t >> 4;          // row group: rows ty*8..+7
    const int row0 = blockIdx.x * 128;

    float acc[8][8];
#pragma unroll
    for (int i = 0; i < 8; ++i)
#pragma unroll
        for (int j = 0; j < 8; ++j) acc[i][j] = 0.f;

    for (int kc = 0; kc < HIDDEN; kc += 32) {
        if (kc) __syncthreads();
        // stage A chunk (transposed): 128 rows x 32 k
#pragma unroll
        for (int pq = 0; pq < 4; ++pq) {
            int id = pq * 256 + t;
            int ro = id >> 3;        // 0..127
            int kq = id & 7;         // 0..7
            int r = row0 + ro;
            if (r > M - 1) r = M - 1;  // clamp: safe read, stores guarded later
            const float4 v = *(const float4*)(A + (size_t)r * HIDDEN + kc + kq * 4);
            As[kq * 4 + 0][ro] = v.x;
            As[kq * 4 + 1][ro] = v.y;
            As[kq * 4 + 2][ro] = v.z;
            As[kq * 4 + 3][ro] = v.w;
        }
        // stage W chunk: 32 k x 128 cols
#pragma unroll
        for (int pq = 0; pq < 4; ++pq) {
            int id = pq * 256 + t;
            int kk = id >> 5;        // 0..31
            int c4 = id & 31;        // 0..31
            *(float4*)(&Ws[kk][c4 * 4]) =
                *(const float4*)(W + (size_t)(kc + kk) * HIDDEN + c4 * 4);
        }
        __syncthreads();
#pragma unroll
        for (int kk = 0; kk < 32; ++kk) {
            float a[8], w[8];
#pragma unroll
            for (int i = 0; i < 8; ++i) a[i] = As[kk][ty * 8 + i];
#pragma unroll
            for (int j = 0; j < 4; ++j) w[j] = Ws[kk][tx * 4 + j];
#pragma unroll
            for (int j = 0; j < 4; ++j) w[4 + j] = Ws[kk][64 + tx * 4 + j];
#pragma unroll
            for (int i = 0; i < 8; ++i)
#pragma unroll
                for (int j = 0; j < 8; ++j) acc[i][j] += a[i] * w[j];
        }
    }

    float bl[8];
#pragma unroll
    for (int j = 0; j < 4; ++j) {
        bl[j]     = bias[tx * 4 + j];
        bl[4 + j] = bias[64 + tx * 4 + j];
    }

#pragma unroll
    for (int i = 0; i < 8; ++i) {
        int r = row0 + ty * 8 + i;
        if (r < M) {
            float4 o0, o1;
            o0.x = fmaxf(acc[i][0] + bl[0], 0.f);
            o0.y = fmaxf(acc[i][1] + bl[1], 0.f);
            o0.z = fmaxf(acc[i][2] + bl[2], 0.f);
            o0.w = fmaxf(acc[i][3] + bl[3], 0.f);
            o1.x = fmaxf(acc[i][4] + bl[4], 0.f);
            o1.y = fmaxf(acc[i][5] + bl[5], 0.f);
            o1.z = fmaxf(acc[i][6] + bl[6], 0.f);
            o1.w = fmaxf(acc[i][7] + bl[7], 0.f);
            *(float4*)(C + (size_t)r * HIDDEN + tx * 4)      = o0;
            *(float4*)(C + (size_t)r * HIDDEN + 64 + tx * 4) = o1;
        }
    }
}

// ---------------------------------------------------------------------------
// Global sum pooling per graph (batch is sorted): block scans 128 contiguous
// nodes, thread f owns feature f, flush one atomicAdd per graph boundary.
// ---------------------------------------------------------------------------
#define POOL_CHUNK 128
__global__ void pool_kernel(const float* __restrict__ X, const int* __restrict__ batch,
                            float* __restrict__ pooled, int layer) {
    const int f = threadIdx.x;  // 0..127
    int start = blockIdx.x * POOL_CHUNK;
    int end = start + POOL_CHUNK;
    if (end > N_NODES) end = N_NODES;
    float acc = 0.f;
    int gcur = batch[start];
    for (int n = start; n < end; ++n) {
        int g = batch[n];
        if (g != gcur) {
            atomicAdd(&pooled[(size_t)gcur * (HIDDEN * N_LAYERS) + layer * HIDDEN + f], acc);
            acc = 0.f;
            gcur = g;
        }
        acc += X[(size_t)n * HIDDEN + f];
    }
    atomicAdd(&pooled[(size_t)gcur * (HIDDEN * N_LAYERS) + layer * HIDDEN + f], acc);
}

// ---------------------------------------------------------------------------
// Classifier head: one block (128 threads) per graph.
// ---------------------------------------------------------------------------
__global__ __launch_bounds__(128) void cls_kernel(const float* __restrict__ pooled,
                                                  const float* __restrict__ w1,
                                                  const float* __restrict__ b1,
                                                  const float* __restrict__ w2,
                                                  const float* __restrict__ b2,
                                                  const float* __restrict__ w3,
                                                  const float* __restrict__ b3,
                                                  float* __restrict__ out) {
    __shared__ float hin[HIDDEN * N_LAYERS];  // 384
    __shared__ float h1[HIDDEN];
    __shared__ float red[HIDDEN];
    const int g = blockIdx.x;
    const int t = threadIdx.x;

    for (int i = t; i < HIDDEN * N_LAYERS; i += 128)
        hin[i] = pooled[(size_t)g * (HIDDEN * N_LAYERS) + i];
    __syncthreads();

    float s = 0.f;
    for (int k = 0; k < HIDDEN * N_LAYERS; ++k) s += hin[k] * w1[(size_t)k * HIDDEN + t];
    s = fmaxf(s + b1[t], 0.f);
    h1[t] = s;
    __syncthreads();

    float s2 = 0.f;
    for (int k = 0; k < HIDDEN; ++k) s2 += h1[k] * w2[(size_t)k * HIDDEN + t];
    s2 = fmaxf(s2 + b2[t], 0.f);

    red[t] = s2 * w3[t];
    __syncthreads();
    for (int off = 64; off > 0; off >>= 1) {
        if (t < off) red[t] += red[t + off];
        __syncthreads();
    }
    if (t == 0) out[g] = red[0] + b3[0];
}

// ---------------------------------------------------------------------------
extern "C" void kernel_launch(void* const* d_in, const int* in_sizes, int n_in,
                              void* d_out, int out_size, void* d_ws, size_t ws_size,
                              hipStream_t stream) {
    const float* X     = (const float*)d_in[0];
    const int*   ei    = (const int*)d_in[1];   // [2, N_EDGES]
    const int*   batch = (const int*)d_in[2];
    const float* w1all = (const float*)d_in[3];
    const float* b1all = (const float*)d_in[4];
    const float* w2all = (const float*)d_in[5];
    const float* b2all = (const float*)d_in[6];
    const float* cw1   = (const float*)d_in[7];
    const float* cb1   = (const float*)d_in[8];
    const float* cw2   = (const float*)d_in[9];
    const float* cb2   = (const float*)d_in[10];
    const float* cw3   = (const float*)d_in[11];
    const float* cb3   = (const float*)d_in[12];
    float* out = (float*)d_out;

    const int* src = ei;            // edge_index[0]
    const int* dst = ei + N_EDGES;  // edge_index[1]

    // workspace carve
    char* p = (char*)d_ws;
    auto alloc = [&](size_t bytes) {
        char* r = p;
        p += (bytes + 255) & ~(size_t)255;
        return r;
    };
    float* bufA    = (float*)alloc((size_t)N_NODES * HIDDEN * sizeof(float));
    float* bufB    = (float*)alloc((size_t)N_NODES * HIDDEN * sizeof(float));
    int*   csr     = (int*)alloc((size_t)N_EDGES * sizeof(int));
    int*   rowp    = (int*)alloc((size_t)(N_NODES + 1) * sizeof(int));
    int*   posb    = (int*)alloc((size_t)N_NODES * sizeof(int));
    int*   deg     = (int*)alloc((size_t)N_NODES * sizeof(int));
    int*   scanned = (int*)alloc((size_t)N_NODES * sizeof(int));
    int*   bsums   = (int*)alloc((size_t)SCAN_NB * sizeof(int));
    float* pooled  = (float*)alloc((size_t)N_GRAPHS * HIDDEN * N_LAYERS * sizeof(float));

    hipMemsetAsync(deg, 0, (size_t)N_NODES * sizeof(int), stream);
    hipMemsetAsync(pooled, 0, (size_t)N_GRAPHS * HIDDEN * N_LAYERS * sizeof(float), stream);

    const int ept_grid = (N_EDGES / 8 + 255) / 256;   // 8 edges per thread
    deg_kernel<<<ept_grid, 256, 0, stream>>>(dst, deg);
    scan_blocks_kernel<<<SCAN_NB, SCAN_BS, 0, stream>>>(deg, scanned, bsums);
    scan_tops_kernel<<<1, 128, 0, stream>>>(bsums);
    scan_finalize_kernel<<<SCAN_NB, SCAN_BS, 0, stream>>>(deg, scanned, bsums, rowp, posb);
    scatter_kernel<<<ept_grid, 256, 0, stream>>>(src, dst, posb, csr);

    // ping-pong buffers: gather out -> mm1 out -> mm2 out (= next layer input)
    const float* Xin = X;
    float* gout[3]   = {bufA, bufB, bufA};
    float* m1out[3]  = {bufB, bufA, bufB};
    float* m2out[3]  = {bufA, bufB, bufA};

    const int mm_grid   = (N_NODES + 127) / 128;
    const int gat_grid  = (N_NODES + 3) / 4;      // 4 waves/block, 1 wave/node
    const int pool_grid = (N_NODES + POOL_CHUNK - 1) / POOL_CHUNK;

    for (int l = 0; l < N_LAYERS; ++l) {
        gather_kernel<<<gat_grid, 256, 0, stream>>>(Xin, gout[l], rowp, csr);
        mm_kernel<<<mm_grid, 256, 0, stream>>>(gout[l],
                                               w1all + (size_t)l * HIDDEN * HIDDEN,
                                               b1all + (size_t)l * HIDDEN,
                                               m1out[l], N_NODES);
        mm_kernel<<<mm_grid, 256, 0, stream>>>(m1out[l],
                                               w2all + (size_t)l * HIDDEN * HIDDEN,
                                               b2all + (size_t)l * HIDDEN,
                                               m2out[l], N_NODES);
        pool_kernel<<<pool_grid, POOL_CHUNK, 0, stream>>>(m2out[l], batch, pooled, l);
        Xin = m2out[l];
    }

    cls_kernel<<<N_GRAPHS, 128, 0, stream>>>(pooled, cw1, cb1, cw2, cb2, cw3, cb3, out);
}

// Round 4
// 1169.495 us; speedup vs baseline: 1.0381x; 1.0381x over previous
//
#include <hip/hip_runtime.h>
#include <cstddef>
#include <cstdint>

#define N_NODES   100000
#define N_EDGES   1600000
#define N_GRAPHS  512
#define HIDDEN    128
#define N_LAYERS  3

#define SCAN_BS   1024
#define SCAN_NB   ((N_NODES + SCAN_BS - 1) / SCAN_BS)   // 98

// XCD partitioning for the CSR build: 8 dst-range slots, 12500 nodes each.
// Block b -> slot (b&7), stripe (b>>3). With round-robin block->XCD dispatch
// each csr/pos/deg cache line is written by exactly ONE XCD => full-line
// dirtying in a single L2 instead of cross-XCD partial-line thrash.
#define NPX       (N_NODES / 8)      // 12500
#define CSR_STRIPES 128
#define CSR_BLOCKS  (CSR_STRIPES * 8)

// ---------------------------------------------------------------------------
__global__ void deg_kernel(const int* __restrict__ dst, int* __restrict__ deg) {
    const int slot   = blockIdx.x & 7;
    const int stripe = blockIdx.x >> 3;
    const int lo = slot * NPX, hi = lo + NPX;
    const int per = (N_EDGES + CSR_STRIPES - 1) / CSR_STRIPES;
    const int e0 = stripe * per;
    int e1 = e0 + per; if (e1 > N_EDGES) e1 = N_EDGES;
    for (int e = e0 + threadIdx.x; e < e1; e += 256) {
        int d = dst[e];
        if (d >= lo && d < hi) atomicAdd(&deg[d], 1);
    }
}

__global__ void scatter_kernel(const int* __restrict__ src, const int* __restrict__ dst,
                               int* __restrict__ pos, int* __restrict__ csr_src) {
    const int slot   = blockIdx.x & 7;
    const int stripe = blockIdx.x >> 3;
    const int lo = slot * NPX, hi = lo + NPX;
    const int per = (N_EDGES + CSR_STRIPES - 1) / CSR_STRIPES;
    const int e0 = stripe * per;
    int e1 = e0 + per; if (e1 > N_EDGES) e1 = N_EDGES;
    for (int e = e0 + threadIdx.x; e < e1; e += 256) {
        int d = dst[e];
        if (d >= lo && d < hi) {
            int p = atomicAdd(&pos[d], 1);
            csr_src[p] = src[e];
        }
    }
}

// per-block inclusive scan of deg -> scanned; per-block totals -> bsums
__global__ __launch_bounds__(SCAN_BS) void scan_blocks_kernel(const int* __restrict__ deg,
                                                              int* __restrict__ scanned,
                                                              int* __restrict__ bsums) {
    __shared__ int tmp[SCAN_BS];
    const int t = threadIdx.x;
    const int i = blockIdx.x * SCAN_BS + t;
    int v = (i < N_NODES) ? deg[i] : 0;
    tmp[t] = v;
    __syncthreads();
#pragma unroll
    for (int off = 1; off < SCAN_BS; off <<= 1) {
        int u = (t >= off) ? tmp[t - off] : 0;
        __syncthreads();
        tmp[t] += u;
        __syncthreads();
    }
    if (i < N_NODES) scanned[i] = tmp[t];
    if (t == SCAN_BS - 1) bsums[blockIdx.x] = tmp[t];
}

// single small block: in-place inclusive scan of the 98 block sums
__global__ __launch_bounds__(128) void scan_tops_kernel(int* __restrict__ bsums) {
    __shared__ int tmp[128];
    const int t = threadIdx.x;
    tmp[t] = (t < SCAN_NB) ? bsums[t] : 0;
    __syncthreads();
#pragma unroll
    for (int off = 1; off < 128; off <<= 1) {
        int u = (t >= off) ? tmp[t - off] : 0;
        __syncthreads();
        tmp[t] += u;
        __syncthreads();
    }
    if (t < SCAN_NB) bsums[t] = tmp[t];
}

// row_ptr[i+1] = offset(b) + scanned[i];  posb[i] = row_ptr[i] (row start)
__global__ __launch_bounds__(SCAN_BS) void scan_finalize_kernel(const int* __restrict__ deg,
                                                                const int* __restrict__ scanned,
                                                                const int* __restrict__ bsums,
                                                                int* __restrict__ row_ptr,
                                                                int* __restrict__ posb) {
    const int b = blockIdx.x;
    const int i = b * SCAN_BS + threadIdx.x;
    if (i >= N_NODES) return;
    const int off = (b > 0) ? bsums[b - 1] : 0;
    const int inc = off + scanned[i];
    row_ptr[i + 1] = inc;
    posb[i] = inc - deg[i];
    if (i == 0) row_ptr[0] = 0;
}

// ---------------------------------------------------------------------------
// GIN aggregation: Z[i] = X[i] + sum_{j in N_in(i)} X[j]
// one wave (64 lanes) per node, float2 per lane => 512B coalesced row reads
// ---------------------------------------------------------------------------
__global__ void gather_kernel(const float* __restrict__ X, float* __restrict__ Z,
                              const int* __restrict__ row_ptr,
                              const int* __restrict__ csr_src) {
    int wave = (blockIdx.x * blockDim.x + threadIdx.x) >> 6;
    int lane = threadIdx.x & 63;
    if (wave >= N_NODES) return;
    const int i = wave;
    float2 acc = ((const float2*)(X + (size_t)i * HIDDEN))[lane];
    int k = row_ptr[i];
    const int end = row_ptr[i + 1];
    // 4-deep unroll: 4 independent row loads in flight to hide LLC latency
    for (; k + 4 <= end; k += 4) {
        int n0 = csr_src[k + 0];
        int n1 = csr_src[k + 1];
        int n2 = csr_src[k + 2];
        int n3 = csr_src[k + 3];
        float2 v0 = ((const float2*)(X + (size_t)n0 * HIDDEN))[lane];
        float2 v1 = ((const float2*)(X + (size_t)n1 * HIDDEN))[lane];
        float2 v2 = ((const float2*)(X + (size_t)n2 * HIDDEN))[lane];
        float2 v3 = ((const float2*)(X + (size_t)n3 * HIDDEN))[lane];
        acc.x += v0.x + v1.x + v2.x + v3.x;
        acc.y += v0.y + v1.y + v2.y + v3.y;
    }
    for (; k < end; ++k) {
        int n = csr_src[k];
        float2 v = ((const float2*)(X + (size_t)n * HIDDEN))[lane];
        acc.x += v.x;
        acc.y += v.y;
    }
    ((float2*)(Z + (size_t)i * HIDDEN))[lane] = acc;
}

// ---------------------------------------------------------------------------
// C[M x 128] = relu(A[M x 128] @ W[128 x 128] + bias)
// 128-row tile / block of 256 threads; 8x8 acc per thread; k staged in LDS
// chunks of 32 with A transposed to [k][row] so all LDS reads are b128-able.
// ---------------------------------------------------------------------------
__global__ __launch_bounds__(256, 4) void mm_kernel(const float* __restrict__ A,
                                                    const float* __restrict__ W,
                                                    const float* __restrict__ bias,
                                                    float* __restrict__ C, int M) {
    __shared__ float As[32][129];   // [k][row], +1 pad
    __shared__ float Ws[32][128];   // [k][col]
    const int t  = threadIdx.x;
    const int tx = t & 15;          // col group: cols tx*4..+3 and 64+tx*4..+3
    const int ty = t >> 4;          // row group: rows ty*8..+7
    const int row0 = blockIdx.x * 128;

    float acc[8][8];
#pragma unroll
    for (int i = 0; i < 8; ++i)
#pragma unroll
        for (int j = 0; j < 8; ++j) acc[i][j] = 0.f;

    for (int kc = 0; kc < HIDDEN; kc += 32) {
        if (kc) __syncthreads();
        // stage A chunk (transposed): 128 rows x 32 k
#pragma unroll
        for (int pq = 0; pq < 4; ++pq) {
            int id = pq * 256 + t;
            int ro = id >> 3;        // 0..127
            int kq = id & 7;         // 0..7
            int r = row0 + ro;
            if (r > M - 1) r = M - 1;  // clamp: safe read, stores guarded later
            const float4 v = *(const float4*)(A + (size_t)r * HIDDEN + kc + kq * 4);
            As[kq * 4 + 0][ro] = v.x;
            As[kq * 4 + 1][ro] = v.y;
            As[kq * 4 + 2][ro] = v.z;
            As[kq * 4 + 3][ro] = v.w;
        }
        // stage W chunk: 32 k x 128 cols
#pragma unroll
        for (int pq = 0; pq < 4; ++pq) {
            int id = pq * 256 + t;
            int kk = id >> 5;        // 0..31
            int c4 = id & 31;        // 0..31
            *(float4*)(&Ws[kk][c4 * 4]) =
                *(const float4*)(W + (size_t)(kc + kk) * HIDDEN + c4 * 4);
        }
        __syncthreads();
#pragma unroll
        for (int kk = 0; kk < 32; ++kk) {
            float a[8], w[8];
#pragma unroll
            for (int i = 0; i < 8; ++i) a[i] = As[kk][ty * 8 + i];
#pragma unroll
            for (int j = 0; j < 4; ++j) w[j] = Ws[kk][tx * 4 + j];
#pragma unroll
            for (int j = 0; j < 4; ++j) w[4 + j] = Ws[kk][64 + tx * 4 + j];
#pragma unroll
            for (int i = 0; i < 8; ++i)
#pragma unroll
                for (int j = 0; j < 8; ++j) acc[i][j] += a[i] * w[j];
        }
    }

    float bl[8];
#pragma unroll
    for (int j = 0; j < 4; ++j) {
        bl[j]     = bias[tx * 4 + j];
        bl[4 + j] = bias[64 + tx * 4 + j];
    }

#pragma unroll
    for (int i = 0; i < 8; ++i) {
        int r = row0 + ty * 8 + i;
        if (r < M) {
            float4 o0, o1;
            o0.x = fmaxf(acc[i][0] + bl[0], 0.f);
            o0.y = fmaxf(acc[i][1] + bl[1], 0.f);
            o0.z = fmaxf(acc[i][2] + bl[2], 0.f);
            o0.w = fmaxf(acc[i][3] + bl[3], 0.f);
            o1.x = fmaxf(acc[i][4] + bl[4], 0.f);
            o1.y = fmaxf(acc[i][5] + bl[5], 0.f);
            o1.z = fmaxf(acc[i][6] + bl[6], 0.f);
            o1.w = fmaxf(acc[i][7] + bl[7], 0.f);
            *(float4*)(C + (size_t)r * HIDDEN + tx * 4)      = o0;
            *(float4*)(C + (size_t)r * HIDDEN + 64 + tx * 4) = o1;
        }
    }
}

// ---------------------------------------------------------------------------
// Global sum pooling per graph (batch is sorted): block scans 128 contiguous
// nodes, thread f owns feature f, flush one atomicAdd per graph boundary.
// ---------------------------------------------------------------------------
#define POOL_CHUNK 128
__global__ void pool_kernel(const float* __restrict__ X, const int* __restrict__ batch,
                            float* __restrict__ pooled, int layer) {
    const int f = threadIdx.x;  // 0..127
    int start = blockIdx.x * POOL_CHUNK;
    int end = start + POOL_CHUNK;
    if (end > N_NODES) end = N_NODES;
    float acc = 0.f;
    int gcur = batch[start];
    for (int n = start; n < end; ++n) {
        int g = batch[n];
        if (g != gcur) {
            atomicAdd(&pooled[(size_t)gcur * (HIDDEN * N_LAYERS) + layer * HIDDEN + f], acc);
            acc = 0.f;
            gcur = g;
        }
        acc += X[(size_t)n * HIDDEN + f];
    }
    atomicAdd(&pooled[(size_t)gcur * (HIDDEN * N_LAYERS) + layer * HIDDEN + f], acc);
}

// ---------------------------------------------------------------------------
// Classifier head: one block (128 threads) per graph.
// ---------------------------------------------------------------------------
__global__ __launch_bounds__(128) void cls_kernel(const float* __restrict__ pooled,
                                                  const float* __restrict__ w1,
                                                  const float* __restrict__ b1,
                                                  const float* __restrict__ w2,
                                                  const float* __restrict__ b2,
                                                  const float* __restrict__ w3,
                                                  const float* __restrict__ b3,
                                                  float* __restrict__ out) {
    __shared__ float hin[HIDDEN * N_LAYERS];  // 384
    __shared__ float h1[HIDDEN];
    __shared__ float red[HIDDEN];
    const int g = blockIdx.x;
    const int t = threadIdx.x;

    for (int i = t; i < HIDDEN * N_LAYERS; i += 128)
        hin[i] = pooled[(size_t)g * (HIDDEN * N_LAYERS) + i];
    __syncthreads();

    float s = 0.f;
    for (int k = 0; k < HIDDEN * N_LAYERS; ++k) s += hin[k] * w1[(size_t)k * HIDDEN + t];
    s = fmaxf(s + b1[t], 0.f);
    h1[t] = s;
    __syncthreads();

    float s2 = 0.f;
    for (int k = 0; k < HIDDEN; ++k) s2 += h1[k] * w2[(size_t)k * HIDDEN + t];
    s2 = fmaxf(s2 + b2[t], 0.f);

    red[t] = s2 * w3[t];
    __syncthreads();
    for (int off = 64; off > 0; off >>= 1) {
        if (t < off) red[t] += red[t + off];
        __syncthreads();
    }
    if (t == 0) out[g] = red[0] + b3[0];
}

// ---------------------------------------------------------------------------
extern "C" void kernel_launch(void* const* d_in, const int* in_sizes, int n_in,
                              void* d_out, int out_size, void* d_ws, size_t ws_size,
                              hipStream_t stream) {
    const float* X     = (const float*)d_in[0];
    const int*   ei    = (const int*)d_in[1];   // [2, N_EDGES]
    const int*   batch = (const int*)d_in[2];
    const float* w1all = (const float*)d_in[3];
    const float* b1all = (const float*)d_in[4];
    const float* w2all = (const float*)d_in[5];
    const float* b2all = (const float*)d_in[6];
    const float* cw1   = (const float*)d_in[7];
    const float* cb1   = (const float*)d_in[8];
    const float* cw2   = (const float*)d_in[9];
    const float* cb2   = (const float*)d_in[10];
    const float* cw3   = (const float*)d_in[11];
    const float* cb3   = (const float*)d_in[12];
    float* out = (float*)d_out;

    const int* src = ei;            // edge_index[0]
    const int* dst = ei + N_EDGES;  // edge_index[1]

    // workspace carve
    char* p = (char*)d_ws;
    auto alloc = [&](size_t bytes) {
        char* r = p;
        p += (bytes + 255) & ~(size_t)255;
        return r;
    };
    float* bufA    = (float*)alloc((size_t)N_NODES * HIDDEN * sizeof(float));
    float* bufB    = (float*)alloc((size_t)N_NODES * HIDDEN * sizeof(float));
    int*   csr     = (int*)alloc((size_t)N_EDGES * sizeof(int));
    int*   rowp    = (int*)alloc((size_t)(N_NODES + 1) * sizeof(int));
    int*   posb    = (int*)alloc((size_t)N_NODES * sizeof(int));
    int*   deg     = (int*)alloc((size_t)N_NODES * sizeof(int));
    int*   scanned = (int*)alloc((size_t)N_NODES * sizeof(int));
    int*   bsums   = (int*)alloc((size_t)SCAN_NB * sizeof(int));
    float* pooled  = (float*)alloc((size_t)N_GRAPHS * HIDDEN * N_LAYERS * sizeof(float));

    hipMemsetAsync(deg, 0, (size_t)N_NODES * sizeof(int), stream);
    hipMemsetAsync(pooled, 0, (size_t)N_GRAPHS * HIDDEN * N_LAYERS * sizeof(float), stream);

    deg_kernel<<<CSR_BLOCKS, 256, 0, stream>>>(dst, deg);
    scan_blocks_kernel<<<SCAN_NB, SCAN_BS, 0, stream>>>(deg, scanned, bsums);
    scan_tops_kernel<<<1, 128, 0, stream>>>(bsums);
    scan_finalize_kernel<<<SCAN_NB, SCAN_BS, 0, stream>>>(deg, scanned, bsums, rowp, posb);
    scatter_kernel<<<CSR_BLOCKS, 256, 0, stream>>>(src, dst, posb, csr);

    // ping-pong buffers: gather out -> mm1 out -> mm2 out (= next layer input)
    const float* Xin = X;
    float* gout[3]   = {bufA, bufB, bufA};
    float* m1out[3]  = {bufB, bufA, bufB};
    float* m2out[3]  = {bufA, bufB, bufA};

    const int mm_grid   = (N_NODES + 127) / 128;
    const int gat_grid  = (N_NODES + 3) / 4;      // 4 waves/block, 1 wave/node
    const int pool_grid = (N_NODES + POOL_CHUNK - 1) / POOL_CHUNK;

    for (int l = 0; l < N_LAYERS; ++l) {
        gather_kernel<<<gat_grid, 256, 0, stream>>>(Xin, gout[l], rowp, csr);
        mm_kernel<<<mm_grid, 256, 0, stream>>>(gout[l],
                                               w1all + (size_t)l * HIDDEN * HIDDEN,
                                               b1all + (size_t)l * HIDDEN,
                                               m1out[l], N_NODES);
        mm_kernel<<<mm_grid, 256, 0, stream>>>(m1out[l],
                                               w2all + (size_t)l * HIDDEN * HIDDEN,
                                               b2all + (size_t)l * HIDDEN,
                                               m2out[l], N_NODES);
        pool_kernel<<<pool_grid, POOL_CHUNK, 0, stream>>>(m2out[l], batch, pooled, l);
        Xin = m2out[l];
    }

    cls_kernel<<<N_GRAPHS, 128, 0, stream>>>(pooled, cw1, cb1, cw2, cb2, cw3, cb3, out);
}

// Round 5
// 1057.443 us; speedup vs baseline: 1.1481x; 1.1060x over previous
//
#include <hip/hip_runtime.h>
#include <hip/hip_fp16.h>
#include <cstddef>
#include <cstdint>

#define N_NODES   100000
#define N_EDGES   1600000
#define N_GRAPHS  512
#define HIDDEN    128
#define N_LAYERS  3

#define SCAN_BS   1024
#define SCAN_NB   ((N_NODES + SCAN_BS - 1) / SCAN_BS)   // 98

// XCD partitioning for the CSR build: 8 dst-range slots, 12500 nodes each.
// Block b -> slot (b&7), stripe (b>>3). With round-robin block->XCD dispatch
// each csr/pos/deg cache line is written by exactly ONE XCD => full-line
// dirtying in a single L2 instead of cross-XCD partial-line thrash.
// [R3->R4: confirmed win, scatter left top-5]
#define NPX       (N_NODES / 8)      // 12500
#define CSR_STRIPES 128
#define CSR_BLOCKS  (CSR_STRIPES * 8)

// ---------------------------------------------------------------------------
__global__ void deg_kernel(const int* __restrict__ dst, int* __restrict__ deg) {
    const int slot   = blockIdx.x & 7;
    const int stripe = blockIdx.x >> 3;
    const int lo = slot * NPX, hi = lo + NPX;
    const int per = (N_EDGES + CSR_STRIPES - 1) / CSR_STRIPES;
    const int e0 = stripe * per;
    int e1 = e0 + per; if (e1 > N_EDGES) e1 = N_EDGES;
    for (int e = e0 + threadIdx.x; e < e1; e += 256) {
        int d = dst[e];
        if (d >= lo && d < hi) atomicAdd(&deg[d], 1);
    }
}

__global__ void scatter_kernel(const int* __restrict__ src, const int* __restrict__ dst,
                               int* __restrict__ pos, int* __restrict__ csr_src) {
    const int slot   = blockIdx.x & 7;
    const int stripe = blockIdx.x >> 3;
    const int lo = slot * NPX, hi = lo + NPX;
    const int per = (N_EDGES + CSR_STRIPES - 1) / CSR_STRIPES;
    const int e0 = stripe * per;
    int e1 = e0 + per; if (e1 > N_EDGES) e1 = N_EDGES;
    for (int e = e0 + threadIdx.x; e < e1; e += 256) {
        int d = dst[e];
        if (d >= lo && d < hi) {
            int p = atomicAdd(&pos[d], 1);
            csr_src[p] = src[e];
        }
    }
}

// per-block inclusive scan of deg -> scanned; per-block totals -> bsums
__global__ __launch_bounds__(SCAN_BS) void scan_blocks_kernel(const int* __restrict__ deg,
                                                              int* __restrict__ scanned,
                                                              int* __restrict__ bsums) {
    __shared__ int tmp[SCAN_BS];
    const int t = threadIdx.x;
    const int i = blockIdx.x * SCAN_BS + t;
    int v = (i < N_NODES) ? deg[i] : 0;
    tmp[t] = v;
    __syncthreads();
#pragma unroll
    for (int off = 1; off < SCAN_BS; off <<= 1) {
        int u = (t >= off) ? tmp[t - off] : 0;
        __syncthreads();
        tmp[t] += u;
        __syncthreads();
    }
    if (i < N_NODES) scanned[i] = tmp[t];
    if (t == SCAN_BS - 1) bsums[blockIdx.x] = tmp[t];
}

// single small block: in-place inclusive scan of the 98 block sums
__global__ __launch_bounds__(128) void scan_tops_kernel(int* __restrict__ bsums) {
    __shared__ int tmp[128];
    const int t = threadIdx.x;
    tmp[t] = (t < SCAN_NB) ? bsums[t] : 0;
    __syncthreads();
#pragma unroll
    for (int off = 1; off < 128; off <<= 1) {
        int u = (t >= off) ? tmp[t - off] : 0;
        __syncthreads();
        tmp[t] += u;
        __syncthreads();
    }
    if (t < SCAN_NB) bsums[t] = tmp[t];
}

// row_ptr[i+1] = offset(b) + scanned[i];  posb[i] = row_ptr[i] (row start)
__global__ __launch_bounds__(SCAN_BS) void scan_finalize_kernel(const int* __restrict__ deg,
                                                                const int* __restrict__ scanned,
                                                                const int* __restrict__ bsums,
                                                                int* __restrict__ row_ptr,
                                                                int* __restrict__ posb) {
    const int b = blockIdx.x;
    const int i = b * SCAN_BS + threadIdx.x;
    if (i >= N_NODES) return;
    const int off = (b > 0) ? bsums[b - 1] : 0;
    const int inc = off + scanned[i];
    row_ptr[i + 1] = inc;
    posb[i] = inc - deg[i];
    if (i == 0) row_ptr[0] = 0;
}

// ---------------------------------------------------------------------------
// fp32 -> fp16 bulk convert (8 elements/thread)
// ---------------------------------------------------------------------------
__global__ void f2h_kernel(const float* __restrict__ in, __half* __restrict__ out) {
    int t = blockIdx.x * blockDim.x + threadIdx.x;
    const int n8 = (N_NODES * HIDDEN) / 8;
    if (t >= n8) return;
    const float4* in4 = (const float4*)in;
    float4 a = in4[t * 2 + 0];
    float4 b = in4[t * 2 + 1];
    __half2* o2 = (__half2*)out;
    o2[t * 4 + 0] = __floats2half2_rn(a.x, a.y);
    o2[t * 4 + 1] = __floats2half2_rn(a.z, a.w);
    o2[t * 4 + 2] = __floats2half2_rn(b.x, b.y);
    o2[t * 4 + 3] = __floats2half2_rn(b.z, b.w);
}

// ---------------------------------------------------------------------------
// GIN aggregation: Z[i] = X_f32[i] + sum_{j in N_in(i)} Xh_f16[j]
// one wave per node; neighbor rows read as fp16 (256 B/row, halves the
// compulsory per-XCD L2-miss traffic that bounds this kernel); fp32 accumulate.
// ---------------------------------------------------------------------------
__global__ void gather_kernel(const float* __restrict__ X, const __half* __restrict__ Xh,
                              float* __restrict__ Z,
                              const int* __restrict__ row_ptr,
                              const int* __restrict__ csr_src) {
    int wave = (blockIdx.x * blockDim.x + threadIdx.x) >> 6;
    int lane = threadIdx.x & 63;
    if (wave >= N_NODES) return;
    const int i = wave;
    float2 acc = ((const float2*)(X + (size_t)i * HIDDEN))[lane];
    const __half2* H = (const __half2*)Xh;   // row stride = 64 half2
    int k = row_ptr[i];
    const int end = row_ptr[i + 1];
    for (; k + 4 <= end; k += 4) {
        int n0 = csr_src[k + 0];
        int n1 = csr_src[k + 1];
        int n2 = csr_src[k + 2];
        int n3 = csr_src[k + 3];
        __half2 v0 = H[(size_t)n0 * 64 + lane];
        __half2 v1 = H[(size_t)n1 * 64 + lane];
        __half2 v2 = H[(size_t)n2 * 64 + lane];
        __half2 v3 = H[(size_t)n3 * 64 + lane];
        float2 f0 = __half22float2(v0);
        float2 f1 = __half22float2(v1);
        float2 f2 = __half22float2(v2);
        float2 f3 = __half22float2(v3);
        acc.x += f0.x + f1.x + f2.x + f3.x;
        acc.y += f0.y + f1.y + f2.y + f3.y;
    }
    for (; k < end; ++k) {
        int n = csr_src[k];
        float2 f = __half22float2(H[(size_t)n * 64 + lane]);
        acc.x += f.x;
        acc.y += f.y;
    }
    ((float2*)(Z + (size_t)i * HIDDEN))[lane] = acc;
}

// ---------------------------------------------------------------------------
// C[M x 128] = relu(A[M x 128] @ W[128 x 128] + bias); optional fp16 twin
// output C16 (used by mm2 so the next layer's gather has its fp16 copy free).
// ---------------------------------------------------------------------------
__global__ __launch_bounds__(256, 4) void mm_kernel(const float* __restrict__ A,
                                                    const float* __restrict__ W,
                                                    const float* __restrict__ bias,
                                                    float* __restrict__ C,
                                                    __half* __restrict__ C16, int M) {
    __shared__ float As[32][129];   // [k][row], +1 pad
    __shared__ float Ws[32][128];   // [k][col]
    const int t  = threadIdx.x;
    const int tx = t & 15;          // col group: cols tx*4..+3 and 64+tx*4..+3
    const int ty = t >> 4;          // row group: rows ty*8..+7
    const int row0 = blockIdx.x * 128;

    float acc[8][8];
#pragma unroll
    for (int i = 0; i < 8; ++i)
#pragma unroll
        for (int j = 0; j < 8; ++j) acc[i][j] = 0.f;

    for (int kc = 0; kc < HIDDEN; kc += 32) {
        if (kc) __syncthreads();
#pragma unroll
        for (int pq = 0; pq < 4; ++pq) {
            int id = pq * 256 + t;
            int ro = id >> 3;        // 0..127
            int kq = id & 7;         // 0..7
            int r = row0 + ro;
            if (r > M - 1) r = M - 1;
            const float4 v = *(const float4*)(A + (size_t)r * HIDDEN + kc + kq * 4);
            As[kq * 4 + 0][ro] = v.x;
            As[kq * 4 + 1][ro] = v.y;
            As[kq * 4 + 2][ro] = v.z;
            As[kq * 4 + 3][ro] = v.w;
        }
#pragma unroll
        for (int pq = 0; pq < 4; ++pq) {
            int id = pq * 256 + t;
            int kk = id >> 5;        // 0..31
            int c4 = id & 31;        // 0..31
            *(float4*)(&Ws[kk][c4 * 4]) =
                *(const float4*)(W + (size_t)(kc + kk) * HIDDEN + c4 * 4);
        }
        __syncthreads();
#pragma unroll
        for (int kk = 0; kk < 32; ++kk) {
            float a[8], w[8];
#pragma unroll
            for (int i = 0; i < 8; ++i) a[i] = As[kk][ty * 8 + i];
#pragma unroll
            for (int j = 0; j < 4; ++j) w[j] = Ws[kk][tx * 4 + j];
#pragma unroll
            for (int j = 0; j < 4; ++j) w[4 + j] = Ws[kk][64 + tx * 4 + j];
#pragma unroll
            for (int i = 0; i < 8; ++i)
#pragma unroll
                for (int j = 0; j < 8; ++j) acc[i][j] += a[i] * w[j];
        }
    }

    float bl[8];
#pragma unroll
    for (int j = 0; j < 4; ++j) {
        bl[j]     = bias[tx * 4 + j];
        bl[4 + j] = bias[64 + tx * 4 + j];
    }

#pragma unroll
    for (int i = 0; i < 8; ++i) {
        int r = row0 + ty * 8 + i;
        if (r < M) {
            float4 o0, o1;
            o0.x = fmaxf(acc[i][0] + bl[0], 0.f);
            o0.y = fmaxf(acc[i][1] + bl[1], 0.f);
            o0.z = fmaxf(acc[i][2] + bl[2], 0.f);
            o0.w = fmaxf(acc[i][3] + bl[3], 0.f);
            o1.x = fmaxf(acc[i][4] + bl[4], 0.f);
            o1.y = fmaxf(acc[i][5] + bl[5], 0.f);
            o1.z = fmaxf(acc[i][6] + bl[6], 0.f);
            o1.w = fmaxf(acc[i][7] + bl[7], 0.f);
            *(float4*)(C + (size_t)r * HIDDEN + tx * 4)      = o0;
            *(float4*)(C + (size_t)r * HIDDEN + 64 + tx * 4) = o1;
            if (C16) {
                __half2* h = (__half2*)(C16 + (size_t)r * HIDDEN + tx * 4);
                h[0] = __floats2half2_rn(o0.x, o0.y);
                h[1] = __floats2half2_rn(o0.z, o0.w);
                __half2* h2 = (__half2*)(C16 + (size_t)r * HIDDEN + 64 + tx * 4);
                h2[0] = __floats2half2_rn(o1.x, o1.y);
                h2[1] = __floats2half2_rn(o1.z, o1.w);
            }
        }
    }
}

// ---------------------------------------------------------------------------
// Global sum pooling per graph (batch is sorted)
// ---------------------------------------------------------------------------
#define POOL_CHUNK 128
__global__ void pool_kernel(const float* __restrict__ X, const int* __restrict__ batch,
                            float* __restrict__ pooled, int layer) {
    const int f = threadIdx.x;  // 0..127
    int start = blockIdx.x * POOL_CHUNK;
    int end = start + POOL_CHUNK;
    if (end > N_NODES) end = N_NODES;
    float acc = 0.f;
    int gcur = batch[start];
    for (int n = start; n < end; ++n) {
        int g = batch[n];
        if (g != gcur) {
            atomicAdd(&pooled[(size_t)gcur * (HIDDEN * N_LAYERS) + layer * HIDDEN + f], acc);
            acc = 0.f;
            gcur = g;
        }
        acc += X[(size_t)n * HIDDEN + f];
    }
    atomicAdd(&pooled[(size_t)gcur * (HIDDEN * N_LAYERS) + layer * HIDDEN + f], acc);
}

// ---------------------------------------------------------------------------
// Classifier head: one block (128 threads) per graph.
// ---------------------------------------------------------------------------
__global__ __launch_bounds__(128) void cls_kernel(const float* __restrict__ pooled,
                                                  const float* __restrict__ w1,
                                                  const float* __restrict__ b1,
                                                  const float* __restrict__ w2,
                                                  const float* __restrict__ b2,
                                                  const float* __restrict__ w3,
                                                  const float* __restrict__ b3,
                                                  float* __restrict__ out) {
    __shared__ float hin[HIDDEN * N_LAYERS];  // 384
    __shared__ float h1[HIDDEN];
    __shared__ float red[HIDDEN];
    const int g = blockIdx.x;
    const int t = threadIdx.x;

    for (int i = t; i < HIDDEN * N_LAYERS; i += 128)
        hin[i] = pooled[(size_t)g * (HIDDEN * N_LAYERS) + i];
    __syncthreads();

    float s = 0.f;
    for (int k = 0; k < HIDDEN * N_LAYERS; ++k) s += hin[k] * w1[(size_t)k * HIDDEN + t];
    s = fmaxf(s + b1[t], 0.f);
    h1[t] = s;
    __syncthreads();

    float s2 = 0.f;
    for (int k = 0; k < HIDDEN; ++k) s2 += h1[k] * w2[(size_t)k * HIDDEN + t];
    s2 = fmaxf(s2 + b2[t], 0.f);

    red[t] = s2 * w3[t];
    __syncthreads();
    for (int off = 64; off > 0; off >>= 1) {
        if (t < off) red[t] += red[t + off];
        __syncthreads();
    }
    if (t == 0) out[g] = red[0] + b3[0];
}

// ---------------------------------------------------------------------------
extern "C" void kernel_launch(void* const* d_in, const int* in_sizes, int n_in,
                              void* d_out, int out_size, void* d_ws, size_t ws_size,
                              hipStream_t stream) {
    const float* X     = (const float*)d_in[0];
    const int*   ei    = (const int*)d_in[1];   // [2, N_EDGES]
    const int*   batch = (const int*)d_in[2];
    const float* w1all = (const float*)d_in[3];
    const float* b1all = (const float*)d_in[4];
    const float* w2all = (const float*)d_in[5];
    const float* b2all = (const float*)d_in[6];
    const float* cw1   = (const float*)d_in[7];
    const float* cb1   = (const float*)d_in[8];
    const float* cw2   = (const float*)d_in[9];
    const float* cb2   = (const float*)d_in[10];
    const float* cw3   = (const float*)d_in[11];
    const float* cb3   = (const float*)d_in[12];
    float* out = (float*)d_out;

    const int* src = ei;            // edge_index[0]
    const int* dst = ei + N_EDGES;  // edge_index[1]

    // workspace carve
    char* p = (char*)d_ws;
    auto alloc = [&](size_t bytes) {
        char* r = p;
        p += (bytes + 255) & ~(size_t)255;
        return r;
    };
    float*  bufA    = (float*)alloc((size_t)N_NODES * HIDDEN * sizeof(float));
    float*  bufB    = (float*)alloc((size_t)N_NODES * HIDDEN * sizeof(float));
    __half* hA      = (__half*)alloc((size_t)N_NODES * HIDDEN * sizeof(__half));
    __half* hB      = (__half*)alloc((size_t)N_NODES * HIDDEN * sizeof(__half));
    int*    csr     = (int*)alloc((size_t)N_EDGES * sizeof(int));
    int*    rowp    = (int*)alloc((size_t)(N_NODES + 1) * sizeof(int));
    int*    posb    = (int*)alloc((size_t)N_NODES * sizeof(int));
    int*    deg     = (int*)alloc((size_t)N_NODES * sizeof(int));
    int*    scanned = (int*)alloc((size_t)N_NODES * sizeof(int));
    int*    bsums   = (int*)alloc((size_t)SCAN_NB * sizeof(int));
    float*  pooled  = (float*)alloc((size_t)N_GRAPHS * HIDDEN * N_LAYERS * sizeof(float));

    hipMemsetAsync(deg, 0, (size_t)N_NODES * sizeof(int), stream);
    hipMemsetAsync(pooled, 0, (size_t)N_GRAPHS * HIDDEN * N_LAYERS * sizeof(float), stream);

    deg_kernel<<<CSR_BLOCKS, 256, 0, stream>>>(dst, deg);
    scan_blocks_kernel<<<SCAN_NB, SCAN_BS, 0, stream>>>(deg, scanned, bsums);
    scan_tops_kernel<<<1, 128, 0, stream>>>(bsums);
    scan_finalize_kernel<<<SCAN_NB, SCAN_BS, 0, stream>>>(deg, scanned, bsums, rowp, posb);
    scatter_kernel<<<CSR_BLOCKS, 256, 0, stream>>>(src, dst, posb, csr);

    // fp16 copy of the layer-0 input
    const int f2h_grid = ((N_NODES * HIDDEN / 8) + 255) / 256;
    f2h_kernel<<<f2h_grid, 256, 0, stream>>>(X, hA);

    // ping-pong: gather out -> mm1 out -> mm2 out (= next layer input)
    const float*  Xin = X;
    float*  gout[3]  = {bufA, bufB, bufA};
    float*  m1out[3] = {bufB, bufA, bufB};
    float*  m2out[3] = {bufA, bufB, bufA};
    __half* hin[3]   = {hA, hB, hA};     // fp16 twin of layer input
    __half* hout[3]  = {hB, hA, hB};     // fp16 twin of layer output (mm2 writes)

    const int mm_grid   = (N_NODES + 127) / 128;
    const int gat_grid  = (N_NODES + 3) / 4;
    const int pool_grid = (N_NODES + POOL_CHUNK - 1) / POOL_CHUNK;

    for (int l = 0; l < N_LAYERS; ++l) {
        gather_kernel<<<gat_grid, 256, 0, stream>>>(Xin, hin[l], gout[l], rowp, csr);
        mm_kernel<<<mm_grid, 256, 0, stream>>>(gout[l],
                                               w1all + (size_t)l * HIDDEN * HIDDEN,
                                               b1all + (size_t)l * HIDDEN,
                                               m1out[l], (__half*)nullptr, N_NODES);
        mm_kernel<<<mm_grid, 256, 0, stream>>>(m1out[l],
                                               w2all + (size_t)l * HIDDEN * HIDDEN,
                                               b2all + (size_t)l * HIDDEN,
                                               m2out[l], hout[l], N_NODES);
        pool_kernel<<<pool_grid, POOL_CHUNK, 0, stream>>>(m2out[l], batch, pooled, l);
        Xin = m2out[l];
    }

    cls_kernel<<<N_GRAPHS, 128, 0, stream>>>(pooled, cw1, cb1, cw2, cb2, cw3, cb3, out);
}

// Round 6
// 815.589 us; speedup vs baseline: 1.4886x; 1.2965x over previous
//
#include <hip/hip_runtime.h>
#include <hip/hip_fp16.h>
#include <cstddef>
#include <cstdint>

#define N_NODES   100000
#define N_EDGES   1600000
#define N_GRAPHS  512
#define HIDDEN    128
#define N_LAYERS  3

#define SCAN_BS   1024
#define SCAN_NB   ((N_NODES + SCAN_BS - 1) / SCAN_BS)   // 98

// XCD partitioning for the CSR build [R4: confirmed win]
#define NPX       (N_NODES / 8)      // 12500
#define CSR_STRIPES 128
#define CSR_BLOCKS  (CSR_STRIPES * 8)
#define EDGES_PER_STRIPE (N_EDGES / CSR_STRIPES)   // 12500, divisible by 4

typedef _Float16 half8 __attribute__((ext_vector_type(8)));
typedef float floatx4 __attribute__((ext_vector_type(4)));

// ---------------------------------------------------------------------------
__global__ void deg_kernel(const int* __restrict__ dst, int* __restrict__ deg) {
    const int slot   = blockIdx.x & 7;
    const int stripe = blockIdx.x >> 3;
    const int lo = slot * NPX, hi = lo + NPX;
    const int4* d4 = (const int4*)(dst + stripe * EDGES_PER_STRIPE);
    const int n4 = EDGES_PER_STRIPE / 4;   // 3125
    for (int i = threadIdx.x; i < n4; i += 256) {
        int4 d = d4[i];
        if (d.x >= lo && d.x < hi) atomicAdd(&deg[d.x], 1);
        if (d.y >= lo && d.y < hi) atomicAdd(&deg[d.y], 1);
        if (d.z >= lo && d.z < hi) atomicAdd(&deg[d.z], 1);
        if (d.w >= lo && d.w < hi) atomicAdd(&deg[d.w], 1);
    }
}

__global__ void scatter_kernel(const int* __restrict__ src, const int* __restrict__ dst,
                               int* __restrict__ pos, int* __restrict__ csr_src) {
    const int slot   = blockIdx.x & 7;
    const int stripe = blockIdx.x >> 3;
    const int lo = slot * NPX, hi = lo + NPX;
    const int4* d4 = (const int4*)(dst + stripe * EDGES_PER_STRIPE);
    const int4* s4 = (const int4*)(src + stripe * EDGES_PER_STRIPE);
    const int n4 = EDGES_PER_STRIPE / 4;
    for (int i = threadIdx.x; i < n4; i += 256) {
        int4 d = d4[i];
        bool any = (d.x >= lo && d.x < hi) || (d.y >= lo && d.y < hi) ||
                   (d.z >= lo && d.z < hi) || (d.w >= lo && d.w < hi);
        if (!any) continue;
        int4 s = s4[i];
        if (d.x >= lo && d.x < hi) { int p = atomicAdd(&pos[d.x], 1); csr_src[p] = s.x; }
        if (d.y >= lo && d.y < hi) { int p = atomicAdd(&pos[d.y], 1); csr_src[p] = s.y; }
        if (d.z >= lo && d.z < hi) { int p = atomicAdd(&pos[d.z], 1); csr_src[p] = s.z; }
        if (d.w >= lo && d.w < hi) { int p = atomicAdd(&pos[d.w], 1); csr_src[p] = s.w; }
    }
}

// per-block inclusive scan of deg -> scanned; per-block totals -> bsums
__global__ __launch_bounds__(SCAN_BS) void scan_blocks_kernel(const int* __restrict__ deg,
                                                              int* __restrict__ scanned,
                                                              int* __restrict__ bsums) {
    __shared__ int tmp[SCAN_BS];
    const int t = threadIdx.x;
    const int i = blockIdx.x * SCAN_BS + t;
    int v = (i < N_NODES) ? deg[i] : 0;
    tmp[t] = v;
    __syncthreads();
#pragma unroll
    for (int off = 1; off < SCAN_BS; off <<= 1) {
        int u = (t >= off) ? tmp[t - off] : 0;
        __syncthreads();
        tmp[t] += u;
        __syncthreads();
    }
    if (i < N_NODES) scanned[i] = tmp[t];
    if (t == SCAN_BS - 1) bsums[blockIdx.x] = tmp[t];
}

__global__ __launch_bounds__(128) void scan_tops_kernel(int* __restrict__ bsums) {
    __shared__ int tmp[128];
    const int t = threadIdx.x;
    tmp[t] = (t < SCAN_NB) ? bsums[t] : 0;
    __syncthreads();
#pragma unroll
    for (int off = 1; off < 128; off <<= 1) {
        int u = (t >= off) ? tmp[t - off] : 0;
        __syncthreads();
        tmp[t] += u;
        __syncthreads();
    }
    if (t < SCAN_NB) bsums[t] = tmp[t];
}

__global__ __launch_bounds__(SCAN_BS) void scan_finalize_kernel(const int* __restrict__ deg,
                                                                const int* __restrict__ scanned,
                                                                const int* __restrict__ bsums,
                                                                int* __restrict__ row_ptr,
                                                                int* __restrict__ posb) {
    const int b = blockIdx.x;
    const int i = b * SCAN_BS + threadIdx.x;
    if (i >= N_NODES) return;
    const int off = (b > 0) ? bsums[b - 1] : 0;
    const int inc = off + scanned[i];
    row_ptr[i + 1] = inc;
    posb[i] = inc - deg[i];
    if (i == 0) row_ptr[0] = 0;
}

// ---------------------------------------------------------------------------
// fp32 -> fp16 bulk convert of X (8 elements/thread)
// ---------------------------------------------------------------------------
__global__ void f2h_kernel(const float* __restrict__ in, __half* __restrict__ out) {
    int t = blockIdx.x * blockDim.x + threadIdx.x;
    const int n8 = (N_NODES * HIDDEN) / 8;
    if (t >= n8) return;
    const float4* in4 = (const float4*)in;
    float4 a = in4[t * 2 + 0];
    float4 b = in4[t * 2 + 1];
    __half2* o2 = (__half2*)out;
    o2[t * 4 + 0] = __floats2half2_rn(a.x, a.y);
    o2[t * 4 + 1] = __floats2half2_rn(a.z, a.w);
    o2[t * 4 + 2] = __floats2half2_rn(b.x, b.y);
    o2[t * 4 + 3] = __floats2half2_rn(b.z, b.w);
}

// Build fp16 transposed weights: wt[l][n][k] = w[l][k][n]  (for MFMA B frags)
__global__ void wconv_kernel(const float* __restrict__ w1, const float* __restrict__ w2,
                             __half* __restrict__ wt1, __half* __restrict__ wt2) {
    int t = blockIdx.x * blockDim.x + threadIdx.x;
    if (t >= N_LAYERS * HIDDEN * HIDDEN) return;
    int l = t / (HIDDEN * HIDDEN);
    int r = t - l * (HIDDEN * HIDDEN);
    int k = r / HIDDEN, n = r - k * HIDDEN;
    wt1[(size_t)l * HIDDEN * HIDDEN + n * HIDDEN + k] = __float2half(w1[t]);
    wt2[(size_t)l * HIDDEN * HIDDEN + n * HIDDEN + k] = __float2half(w2[t]);
}

// ---------------------------------------------------------------------------
// GIN aggregation, all-fp16 io: Z[i] = Xh[i] + sum_{j in N_in(i)} Xh[j]
// one wave per node, half2/lane; fp32 accumulate. Bound by compulsory
// per-XCD L2 misses on the random neighbor rows (~8 x 25.6 MB).
// ---------------------------------------------------------------------------
__global__ void gather_kernel(const __half* __restrict__ Xh, __half* __restrict__ Zh,
                              const int* __restrict__ row_ptr,
                              const int* __restrict__ csr_src) {
    int wave = (blockIdx.x * blockDim.x + threadIdx.x) >> 6;
    int lane = threadIdx.x & 63;
    if (wave >= N_NODES) return;
    const __half2* H = (const __half2*)Xh;   // row stride = 64 half2
    float2 acc = __half22float2(H[(size_t)wave * 64 + lane]);
    int k = row_ptr[wave];
    const int end = row_ptr[wave + 1];
    for (; k + 4 <= end; k += 4) {
        int n0 = csr_src[k + 0];
        int n1 = csr_src[k + 1];
        int n2 = csr_src[k + 2];
        int n3 = csr_src[k + 3];
        float2 f0 = __half22float2(H[(size_t)n0 * 64 + lane]);
        float2 f1 = __half22float2(H[(size_t)n1 * 64 + lane]);
        float2 f2 = __half22float2(H[(size_t)n2 * 64 + lane]);
        float2 f3 = __half22float2(H[(size_t)n3 * 64 + lane]);
        acc.x += f0.x + f1.x + f2.x + f3.x;
        acc.y += f0.y + f1.y + f2.y + f3.y;
    }
    for (; k < end; ++k) {
        int n = csr_src[k];
        float2 f = __half22float2(H[(size_t)n * 64 + lane]);
        acc.x += f.x;
        acc.y += f.y;
    }
    ((__half2*)Zh)[(size_t)wave * 64 + lane] = __floats2half2_rn(acc.x, acc.y);
}

// ---------------------------------------------------------------------------
// MFMA GEMM: C[M x 128] = relu(A[M x 128] @ W + bias), A fp16, Wt = W^T fp16.
// mfma_f32_16x16x32_f16; verified layouts: A[m=lane&15][k=quad*8+j],
// B[k][n]: n=lane&15, k=quad*8+j (from Wt rows), C/D col=lane&15,
// row=quad*4+reg. All frags loaded straight from global (Wt is L2-hot).
// One wave = 16 rows x 128 cols; block = 4 waves = 64 rows.
// ---------------------------------------------------------------------------
__global__ __launch_bounds__(256) void mm16_kernel(const __half* __restrict__ A,
                                                   const __half* __restrict__ Wt,
                                                   const float* __restrict__ bias,
                                                   float* __restrict__ C32,
                                                   __half* __restrict__ C16, int M) {
    const int wave = threadIdx.x >> 6;
    const int lane = threadIdx.x & 63;
    const int m = lane & 15;
    const int q = lane >> 4;          // quad
    const int row0 = blockIdx.x * 64 + wave * 16;

    int ra = row0 + m; if (ra > M - 1) ra = M - 1;   // clamp loads; stores guarded
    const half8* Arow = (const half8*)(A + (size_t)ra * HIDDEN);
    half8 a0 = Arow[q];
    half8 a1 = Arow[4 + q];
    half8 a2 = Arow[8 + q];
    half8 a3 = Arow[12 + q];

#pragma unroll
    for (int ct = 0; ct < 8; ++ct) {
        const int n = ct * 16 + m;
        const half8* Wrow = (const half8*)(Wt + (size_t)n * HIDDEN);
        floatx4 acc = {0.f, 0.f, 0.f, 0.f};
        acc = __builtin_amdgcn_mfma_f32_16x16x32_f16(a0, Wrow[q],      acc, 0, 0, 0);
        acc = __builtin_amdgcn_mfma_f32_16x16x32_f16(a1, Wrow[4 + q],  acc, 0, 0, 0);
        acc = __builtin_amdgcn_mfma_f32_16x16x32_f16(a2, Wrow[8 + q],  acc, 0, 0, 0);
        acc = __builtin_amdgcn_mfma_f32_16x16x32_f16(a3, Wrow[12 + q], acc, 0, 0, 0);
        const float b = bias[n];
#pragma unroll
        for (int r = 0; r < 4; ++r) {
            int row = row0 + q * 4 + r;
            if (row < M) {
                float v = fmaxf(acc[r] + b, 0.f);
                if (C32) C32[(size_t)row * HIDDEN + n] = v;
                if (C16) C16[(size_t)row * HIDDEN + n] = __float2half(v);
            }
        }
    }
}

// ---------------------------------------------------------------------------
// Global sum pooling per graph (batch sorted), fp16 input, fp32 accumulate.
// ---------------------------------------------------------------------------
#define POOL_CHUNK 128
__global__ void pool_kernel(const __half* __restrict__ Xh, const int* __restrict__ batch,
                            float* __restrict__ pooled, int layer) {
    const int f = threadIdx.x;  // 0..127
    int start = blockIdx.x * POOL_CHUNK;
    int end = start + POOL_CHUNK;
    if (end > N_NODES) end = N_NODES;
    float acc = 0.f;
    int gcur = batch[start];
    for (int n = start; n < end; ++n) {
        int g = batch[n];
        if (g != gcur) {
            atomicAdd(&pooled[(size_t)gcur * (HIDDEN * N_LAYERS) + layer * HIDDEN + f], acc);
            acc = 0.f;
            gcur = g;
        }
        acc += __half2float(Xh[(size_t)n * HIDDEN + f]);
    }
    atomicAdd(&pooled[(size_t)gcur * (HIDDEN * N_LAYERS) + layer * HIDDEN + f], acc);
}

// ---------------------------------------------------------------------------
// Classifier head: one block (128 threads) per graph. fp32 (tiny).
// ---------------------------------------------------------------------------
__global__ __launch_bounds__(128) void cls_kernel(const float* __restrict__ pooled,
                                                  const float* __restrict__ w1,
                                                  const float* __restrict__ b1,
                                                  const float* __restrict__ w2,
                                                  const float* __restrict__ b2,
                                                  const float* __restrict__ w3,
                                                  const float* __restrict__ b3,
                                                  float* __restrict__ out) {
    __shared__ float hin[HIDDEN * N_LAYERS];  // 384
    __shared__ float h1[HIDDEN];
    __shared__ float red[HIDDEN];
    const int g = blockIdx.x;
    const int t = threadIdx.x;

    for (int i = t; i < HIDDEN * N_LAYERS; i += 128)
        hin[i] = pooled[(size_t)g * (HIDDEN * N_LAYERS) + i];
    __syncthreads();

    float s = 0.f;
    for (int k = 0; k < HIDDEN * N_LAYERS; ++k) s += hin[k] * w1[(size_t)k * HIDDEN + t];
    s = fmaxf(s + b1[t], 0.f);
    h1[t] = s;
    __syncthreads();

    float s2 = 0.f;
    for (int k = 0; k < HIDDEN; ++k) s2 += h1[k] * w2[(size_t)k * HIDDEN + t];
    s2 = fmaxf(s2 + b2[t], 0.f);

    red[t] = s2 * w3[t];
    __syncthreads();
    for (int off = 64; off > 0; off >>= 1) {
        if (t < off) red[t] += red[t + off];
        __syncthreads();
    }
    if (t == 0) out[g] = red[0] + b3[0];
}

// ---------------------------------------------------------------------------
extern "C" void kernel_launch(void* const* d_in, const int* in_sizes, int n_in,
                              void* d_out, int out_size, void* d_ws, size_t ws_size,
                              hipStream_t stream) {
    const float* X     = (const float*)d_in[0];
    const int*   ei    = (const int*)d_in[1];   // [2, N_EDGES]
    const int*   batch = (const int*)d_in[2];
    const float* w1all = (const float*)d_in[3];
    const float* b1all = (const float*)d_in[4];
    const float* w2all = (const float*)d_in[5];
    const float* b2all = (const float*)d_in[6];
    const float* cw1   = (const float*)d_in[7];
    const float* cb1   = (const float*)d_in[8];
    const float* cw2   = (const float*)d_in[9];
    const float* cb2   = (const float*)d_in[10];
    const float* cw3   = (const float*)d_in[11];
    const float* cb3   = (const float*)d_in[12];
    float* out = (float*)d_out;

    const int* src = ei;            // edge_index[0]
    const int* dst = ei + N_EDGES;  // edge_index[1]

    // workspace carve
    char* p = (char*)d_ws;
    auto alloc = [&](size_t bytes) {
        char* r = p;
        p += (bytes + 255) & ~(size_t)255;
        return r;
    };
    __half* hA      = (__half*)alloc((size_t)N_NODES * HIDDEN * sizeof(__half));
    __half* hB      = (__half*)alloc((size_t)N_NODES * HIDDEN * sizeof(__half));
    __half* zh      = (__half*)alloc((size_t)N_NODES * HIDDEN * sizeof(__half));
    __half* m1h     = (__half*)alloc((size_t)N_NODES * HIDDEN * sizeof(__half));
    __half* wt1     = (__half*)alloc((size_t)N_LAYERS * HIDDEN * HIDDEN * sizeof(__half));
    __half* wt2     = (__half*)alloc((size_t)N_LAYERS * HIDDEN * HIDDEN * sizeof(__half));
    int*    csr     = (int*)alloc((size_t)N_EDGES * sizeof(int));
    int*    rowp    = (int*)alloc((size_t)(N_NODES + 1) * sizeof(int));
    int*    posb    = (int*)alloc((size_t)N_NODES * sizeof(int));
    int*    deg     = (int*)alloc((size_t)N_NODES * sizeof(int));
    int*    scanned = (int*)alloc((size_t)N_NODES * sizeof(int));
    int*    bsums   = (int*)alloc((size_t)SCAN_NB * sizeof(int));
    float*  pooled  = (float*)alloc((size_t)N_GRAPHS * HIDDEN * N_LAYERS * sizeof(float));

    hipMemsetAsync(deg, 0, (size_t)N_NODES * sizeof(int), stream);
    hipMemsetAsync(pooled, 0, (size_t)N_GRAPHS * HIDDEN * N_LAYERS * sizeof(float), stream);

    deg_kernel<<<CSR_BLOCKS, 256, 0, stream>>>(dst, deg);
    scan_blocks_kernel<<<SCAN_NB, SCAN_BS, 0, stream>>>(deg, scanned, bsums);
    scan_tops_kernel<<<1, 128, 0, stream>>>(bsums);
    scan_finalize_kernel<<<SCAN_NB, SCAN_BS, 0, stream>>>(deg, scanned, bsums, rowp, posb);
    scatter_kernel<<<CSR_BLOCKS, 256, 0, stream>>>(src, dst, posb, csr);

    const int f2h_grid = ((N_NODES * HIDDEN / 8) + 255) / 256;
    f2h_kernel<<<f2h_grid, 256, 0, stream>>>(X, hA);
    wconv_kernel<<<(N_LAYERS * HIDDEN * HIDDEN + 255) / 256, 256, 0, stream>>>(w1all, w2all, wt1, wt2);

    const int mm_grid   = (N_NODES + 63) / 64;     // 1563
    const int gat_grid  = (N_NODES + 3) / 4;
    const int pool_grid = (N_NODES + POOL_CHUNK - 1) / POOL_CHUNK;

    __half* hcur = hA;
    for (int l = 0; l < N_LAYERS; ++l) {
        __half* hnext = (l & 1) ? hA : hB;
        gather_kernel<<<gat_grid, 256, 0, stream>>>(hcur, zh, rowp, csr);
        mm16_kernel<<<mm_grid, 256, 0, stream>>>(zh,
                                                 wt1 + (size_t)l * HIDDEN * HIDDEN,
                                                 b1all + (size_t)l * HIDDEN,
                                                 (float*)nullptr, m1h, N_NODES);
        mm16_kernel<<<mm_grid, 256, 0, stream>>>(m1h,
                                                 wt2 + (size_t)l * HIDDEN * HIDDEN,
                                                 b2all + (size_t)l * HIDDEN,
                                                 (float*)nullptr, hnext, N_NODES);
        pool_kernel<<<pool_grid, POOL_CHUNK, 0, stream>>>(hnext, batch, pooled, l);
        hcur = hnext;
    }

    cls_kernel<<<N_GRAPHS, 128, 0, stream>>>(pooled, cw1, cb1, cw2, cb2, cw3, cb3, out);
}